// Round 9
// baseline (53.928 us; speedup 1.0000x reference)
//
#include <hip/hip_runtime.h>
#include <hip/hip_bf16.h>
#include <stdint.h>

typedef short bfx8 __attribute__((ext_vector_type(8)));
typedef float f32x4 __attribute__((ext_vector_type(4)));

#define MFMA16(a, b, c) __builtin_amdgcn_mfma_f32_16x16x32_bf16(a, b, c, 0, 0, 0)
// 0x77: ALU/VALU/SALU/VMEM may cross; DS_READ/DS_WRITE/MFMA pinned
#define STAGE_FENCE() __builtin_amdgcn_sched_barrier(0x77)
// 0x47: additionally pins VMEM_READ (keeps prefetch loads ABOVE this point)
#define PIN_FENCE()   __builtin_amdgcn_sched_barrier(0x47)

// cb layout (floats)
#define CB_B1  0
#define CB_B2  64
#define CB_AB1 128
#define CB_AB2 192
#define CB_A3  256
#define CB_AB3 320

__device__ __forceinline__ uint32_t pk2(float a, float b) {
    __hip_bfloat162 h = __float22bfloat162_rn(make_float2(a, b)); // low=a, high=b
    union { __hip_bfloat162 h; uint32_t u; } cv; cv.h = h; return cv.u;
}
__device__ __forceinline__ float bflo(uint32_t w) { return __uint_as_float(w << 16); }
__device__ __forceinline__ float bfhi(uint32_t w) { return __uint_as_float(w & 0xFFFF0000u); }

__device__ __forceinline__ bfx8 pack8(const float4 a, const float4 b) {
    union { bfx8 v; uint32_t u[4]; } r;
    r.u[0] = pk2(a.x, a.y); r.u[1] = pk2(a.z, a.w);
    r.u[2] = pk2(b.x, b.y); r.u[3] = pk2(b.z, b.w);
    return r.v;
}
// relu + pack two acc quads (a = dims +0..3, b = dims +4..7)
__device__ __forceinline__ bfx8 packr(f32x4 a, f32x4 b) {
    union { bfx8 v; uint32_t u[4]; } r;
    r.u[0] = pk2(fmaxf(a[0], 0.f), fmaxf(a[1], 0.f));
    r.u[1] = pk2(fmaxf(a[2], 0.f), fmaxf(a[3], 0.f));
    r.u[2] = pk2(fmaxf(b[0], 0.f), fmaxf(b[1], 0.f));
    r.u[3] = pk2(fmaxf(b[2], 0.f), fmaxf(b[3], 0.f));
    return r.v;
}
__device__ __forceinline__ float4 ld4(const float* p) { return *(const float4*)p; }

// bank-spread XOR mixes (row bits that vary across the 16 A-rows: 0,1,3,4)
__device__ __forceinline__ int mix4(int row) {
    return (row & 3) | (((row >> 4) & 1) << 2) | (((row >> 3) & 1) << 3);
}
__device__ __forceinline__ int mix3(int row) {
    return (row & 3) | (((row >> 3) & 1) << 2);
}
// weight fragment loads: 256B-row (K=128) and 128B-row (K=64) arrays
__device__ __forceinline__ bfx8 ldw4(const uint8_t* base, int row, int c, int g) {
    int chunk = (4 * c + g) ^ mix4(row);
    return *(const bfx8*)(base + row * 256 + chunk * 16);
}
__device__ __forceinline__ bfx8 ldw2(const uint8_t* base, int row, int c, int g) {
    int chunk = ((4 * c + g) ^ mix3(row)) & 7;
    return *(const bfx8*)(base + row * 128 + chunk * 16);
}
// DPP 16-lane row reduction (VALU only, no LDS); ctrl must be compile-time
template <int CTRL>
__device__ __forceinline__ float dppadd(float x) {
    int y = __builtin_amdgcn_update_dpp(0, __float_as_int(x), CTRL, 0xF, 0xF, false);
    return x + __int_as_float(y);
}
__device__ __forceinline__ float rowsum16(float x) {
    x = dppadd<0xB1>(x);    // quad_perm(1,0,3,2) : xor1
    x = dppadd<0x4E>(x);    // quad_perm(2,3,0,1) : xor2
    x = dppadd<0x124>(x);   // row_ror:4
    x = dppadd<0x128>(x);   // row_ror:8
    return x;
}

__global__ __launch_bounds__(512, 1) void uvagg_mfma(
    const int* __restrict__ nodes, const int* __restrict__ huv,
    const int* __restrict__ hr, const int* __restrict__ hlen,
    const float* __restrict__ v2e, const float* __restrict__ u2e,
    const float* __restrict__ r2e,
    const float* __restrict__ W1, const float* __restrict__ b1,
    const float* __restrict__ W2, const float* __restrict__ b2,
    const float* __restrict__ A1, const float* __restrict__ ab1,
    const float* __restrict__ A2, const float* __restrict__ ab2,
    const float* __restrict__ A3, const float* __restrict__ ab3f,
    float* __restrict__ out, int N, int L, int nwaves)
{
    __shared__ __align__(16) uint8_t W1s[64 * 256];
    __shared__ __align__(16) uint8_t A1s[64 * 256];
    __shared__ __align__(16) uint8_t W2s[64 * 128];
    __shared__ __align__(16) uint8_t A2s[64 * 128];
    __shared__ __align__(16) float cb[324];

    const int tid = threadIdx.x;
    // stage W1/A1: 4096 k-pairs each; thread handles (2kp, 2kp+1) x d
    for (int i = tid; i < 4096; i += 512) {
        int kp = i >> 6, d = i & 63;
        int addr = d * 256 + ((((kp >> 2) ^ mix4(d)) & 15) << 4) + ((kp & 3) << 2);
        *(uint32_t*)(W1s + addr) = pk2(W1[(2 * kp) * 64 + d], W1[(2 * kp + 1) * 64 + d]);
        *(uint32_t*)(A1s + addr) = pk2(A1[(2 * kp) * 64 + d], A1[(2 * kp + 1) * 64 + d]);
    }
    // stage W2/A2: 2048 k-pairs each
    for (int i = tid; i < 2048; i += 512) {
        int kp = i >> 6, d = i & 63;
        int addr = d * 128 + ((((kp >> 2) ^ mix3(d)) & 7) << 4) + ((kp & 3) << 2);
        *(uint32_t*)(W2s + addr) = pk2(W2[(2 * kp) * 64 + d], W2[(2 * kp + 1) * 64 + d]);
        *(uint32_t*)(A2s + addr) = pk2(A2[(2 * kp) * 64 + d], A2[(2 * kp + 1) * 64 + d]);
    }
    for (int i = tid; i < 321; i += 512) {
        if (i < 64)       cb[CB_B1 + i]        = b1[i];
        else if (i < 128) cb[CB_B2 + i - 64]   = b2[i - 64];
        else if (i < 192) cb[CB_AB1 + i - 128] = ab1[i - 128];
        else if (i < 256) cb[CB_AB2 + i - 192] = ab2[i - 192];
        else if (i < 320) cb[CB_A3 + i - 256]  = A3[i - 256];
        else              cb[CB_AB3]           = ab3f[0];
    }
    __syncthreads();

    const int lane = tid & 63;
    const int wid  = tid >> 6;
    const int s    = lane & 15;          // slot-in-tile (matrix column)
    const int g    = lane >> 4;          // k-group
    const int rs   = 8 * (s >> 2) + (s & 3);  // pi-permuted A-row base
    const float ab3 = cb[CB_AB3];

    for (int node = blockIdx.x * 8 + wid; node < N; node += nwaves) {
        const int hl = __builtin_amdgcn_readfirstlane(min(hlen[node], L));
        const int un = __builtin_amdgcn_readfirstlane(nodes[node]);

        // urep B-frags: A1 k-cols 64..127 (natural k order)
        const float* ur = u2e + (size_t)un * 64;
        const bfx8 uf2 = pack8(ld4(ur + 8 * g),      ld4(ur + 8 * g + 4));
        const bfx8 uf3 = pack8(ld4(ur + 32 + 8 * g), ld4(ur + 36 + 8 * g));

        // preload ALL history indices for this node (lane-spread, one level)
        const int idxlane = min(lane, L - 1);
        const int iu_all = huv[(size_t)node * L + idxlane];
        const int ir_all = hr [(size_t)node * L + idxlane];

        float zacc = 0.0f;
        f32x4 accO[4];
        #pragma unroll
        for (int i = 0; i < 4; ++i) accO[i] = f32x4{0.f, 0.f, 0.f, 0.f};

        const int ntile = (hl + 15) >> 4;

        // ---- pipeline prologue: issue tile-0 embedding loads
        float4 qa0, qa1, qa2, qa3, qb0, qb1, qb2, qb3;
        {
            const int slot0 = min(s, hl - 1);
            const int iu = __shfl(iu_all, slot0, 64);
            const int ir = __shfl(ir_all, slot0, 64);
            const float* vr = v2e + (size_t)iu * 64;
            const float* rr = r2e + (size_t)ir * 64;
            qa0 = ld4(vr + 8 * g);      qa1 = ld4(vr + 8 * g + 4);
            qa2 = ld4(vr + 32 + 8 * g); qa3 = ld4(vr + 36 + 8 * g);
            qb0 = ld4(rr + 8 * g);      qb1 = ld4(rr + 8 * g + 4);
            qb2 = ld4(rr + 32 + 8 * g); qb3 = ld4(rr + 36 + 8 * g);
        }

        for (int tt = 0; tt < ntile; ++tt) {
            const int gslot = tt * 16 + s;
            // pack current tile's fragments from prefetched raw floats
            const bfx8 f0 = pack8(qa0, qa1);
            const bfx8 f1 = pack8(qa2, qa3);
            const bfx8 f2 = pack8(qb0, qb1);
            const bfx8 f3 = pack8(qb2, qb3);

            // ---- stage 1: x1 = relu(W1^T X + b1), pi-permuted rows
            f32x4 ah[4];
            #pragma unroll
            for (int mt = 0; mt < 4; ++mt) {
                const int dof = 4 * (mt & 1) + 32 * (mt >> 1);
                ah[mt] = *(const f32x4*)(cb + CB_B1 + 8 * g + dof);
                const int row = rs + dof;
                ah[mt] = MFMA16(ldw4(W1s, row, 0, g), f0, ah[mt]);
                ah[mt] = MFMA16(ldw4(W1s, row, 1, g), f1, ah[mt]);
                ah[mt] = MFMA16(ldw4(W1s, row, 2, g), f2, ah[mt]);
                ah[mt] = MFMA16(ldw4(W1s, row, 3, g), f3, ah[mt]);
            }
            const bfx8 x1a = packr(ah[0], ah[1]);   // dims 8g..8g+7
            const bfx8 x1b = packr(ah[2], ah[3]);   // dims 32+8g..

            // ---- prefetch next tile's embeddings (wave-uniform guard);
            //      they land during stages 2-4 (~600+ cy of cover)
            if (tt + 1 < ntile) {
                const int nslot = min(tt * 16 + 16 + s, hl - 1);
                const int niu = __shfl(iu_all, nslot, 64);
                const int nir = __shfl(ir_all, nslot, 64);
                const float* vr = v2e + (size_t)niu * 64;
                const float* rr = r2e + (size_t)nir * 64;
                qa0 = ld4(vr + 8 * g);      qa1 = ld4(vr + 8 * g + 4);
                qa2 = ld4(vr + 32 + 8 * g); qa3 = ld4(vr + 36 + 8 * g);
                qb0 = ld4(rr + 8 * g);      qb1 = ld4(rr + 8 * g + 4);
                qb2 = ld4(rr + 32 + 8 * g); qb3 = ld4(rr + 36 + 8 * g);
            }
            PIN_FENCE();   // VMEM_READ may not sink below here

            // ---- stage 2: o = relu(W2^T x1 + b2); immediately pack to bf16
            f32x4 ao[4];
            #pragma unroll
            for (int mt = 0; mt < 4; ++mt) {
                const int dof = 4 * (mt & 1) + 32 * (mt >> 1);
                ao[mt] = *(const f32x4*)(cb + CB_B2 + 8 * g + dof);
                const int row = rs + dof;
                ao[mt] = MFMA16(ldw2(W2s, row, 0, g), x1a, ao[mt]);
                ao[mt] = MFMA16(ldw2(W2s, row, 1, g), x1b, ao[mt]);
            }
            const bfx8 oa = packr(ao[0], ao[1]);
            const bfx8 ob = packr(ao[2], ao[3]);
            STAGE_FENCE();

            // ---- stage 3: h1 = relu(A1^T [o; urep] + ab1)
            f32x4 h[4];
            #pragma unroll
            for (int mt = 0; mt < 4; ++mt) {
                const int dof = 4 * (mt & 1) + 32 * (mt >> 1);
                h[mt] = *(const f32x4*)(cb + CB_AB1 + 8 * g + dof);
                const int row = rs + dof;
                h[mt] = MFMA16(ldw4(A1s, row, 0, g), oa,  h[mt]);
                h[mt] = MFMA16(ldw4(A1s, row, 1, g), ob,  h[mt]);
                h[mt] = MFMA16(ldw4(A1s, row, 2, g), uf2, h[mt]);
                h[mt] = MFMA16(ldw4(A1s, row, 3, g), uf3, h[mt]);
            }
            const bfx8 h1a = packr(h[0], h[1]);
            const bfx8 h1b = packr(h[2], h[3]);
            STAGE_FENCE();

            // ---- stage 4: h2 = relu(A2^T h1 + ab2); fused logit dot with A3
            float part = 0.0f;
            #pragma unroll
            for (int mt = 0; mt < 4; ++mt) {
                const int dof = 4 * (mt & 1) + 32 * (mt >> 1);
                f32x4 h2 = *(const f32x4*)(cb + CB_AB2 + 8 * g + dof);
                const int row = rs + dof;
                h2 = MFMA16(ldw2(A2s, row, 0, g), h1a, h2);
                h2 = MFMA16(ldw2(A2s, row, 1, g), h1b, h2);
                const f32x4 aq = *(const f32x4*)(cb + CB_A3 + 8 * g + dof);
                part = fmaf(fmaxf(h2[0], 0.f), aq[0], part);
                part = fmaf(fmaxf(h2[1], 0.f), aq[1], part);
                part = fmaf(fmaxf(h2[2], 0.f), aq[2], part);
                part = fmaf(fmaxf(h2[3], 0.f), aq[3], part);
            }
            STAGE_FENCE();
            // cross-g reduce (lanes s, s+16, s+32, s+48)
            float p2 = part + __shfl_xor(part, 16, 64);
            const float sl = p2 + __shfl_xor(p2, 32, 64) + ab3;
            // no-max softmax (logits are tiny; exp is exact softmax up to shift)
            const float p = (gslot < hl) ? __expf(sl) : 0.0f;
            zacc += p;
            // accumulate p * o from the bf16-packed oa/ob (unpack = shift/mask)
            union { bfx8 v; uint32_t u[4]; } ua, ub;
            ua.v = oa; ub.v = ob;
            #pragma unroll
            for (int j = 0; j < 2; ++j) {
                accO[0][2*j+0] = fmaf(p, bflo(ua.u[j]),     accO[0][2*j+0]);
                accO[0][2*j+1] = fmaf(p, bfhi(ua.u[j]),     accO[0][2*j+1]);
                accO[1][2*j+0] = fmaf(p, bflo(ua.u[2 + j]), accO[1][2*j+0]);
                accO[1][2*j+1] = fmaf(p, bfhi(ua.u[2 + j]), accO[1][2*j+1]);
                accO[2][2*j+0] = fmaf(p, bflo(ub.u[j]),     accO[2][2*j+0]);
                accO[2][2*j+1] = fmaf(p, bfhi(ub.u[j]),     accO[2][2*j+1]);
                accO[3][2*j+0] = fmaf(p, bflo(ub.u[2 + j]), accO[3][2*j+0]);
                accO[3][2*j+1] = fmaf(p, bfhi(ub.u[2 + j]), accO[3][2*j+1]);
            }
        }

        // final reductions over the 16 slot-lanes: DPP only
        const float Z = rowsum16(zacc);
        #pragma unroll
        for (int mt = 0; mt < 4; ++mt)
            #pragma unroll
            for (int r = 0; r < 4; ++r)
                accO[mt][r] = rowsum16(accO[mt][r]);
        const float inv = 1.0f / Z;
        if (s == 0) {
            float* op = out + (size_t)node * 64;
            #pragma unroll
            for (int mt = 0; mt < 4; ++mt) {
                const int dof = 8 * g + 4 * (mt & 1) + 32 * (mt >> 1);
                *(float4*)(op + dof) = make_float4(accO[mt][0] * inv, accO[mt][1] * inv,
                                                   accO[mt][2] * inv, accO[mt][3] * inv);
            }
        }
    }
}

extern "C" void kernel_launch(void* const* d_in, const int* in_sizes, int n_in,
                              void* d_out, int out_size, void* d_ws, size_t ws_size,
                              hipStream_t stream) {
    const int*   nodes = (const int*)d_in[0];
    const int*   huv   = (const int*)d_in[1];
    const int*   hrr   = (const int*)d_in[2];
    const int*   hlen  = (const int*)d_in[3];
    const float* v2e   = (const float*)d_in[4];
    const float* u2e   = (const float*)d_in[5];
    const float* r2e   = (const float*)d_in[6];
    const float* W1    = (const float*)d_in[7];
    const float* b1    = (const float*)d_in[8];
    const float* W2    = (const float*)d_in[9];
    const float* b2    = (const float*)d_in[10];
    const float* A1    = (const float*)d_in[11];
    const float* ab1   = (const float*)d_in[12];
    const float* A2    = (const float*)d_in[13];
    const float* ab2   = (const float*)d_in[14];
    const float* A3    = (const float*)d_in[15];
    const float* ab3   = (const float*)d_in[16];
    float* out = (float*)d_out;

    const int N = in_sizes[0];
    const int L = in_sizes[1] / N;
    const int blocks = (N + 7) / 8;       // 1 node per wave, 8 waves per block
    const int nwaves = blocks * 8;

    hipLaunchKernelGGL(uvagg_mfma, dim3(blocks), dim3(512), 0, stream,
                       nodes, huv, hrr, hlen, v2e, u2e, r2e,
                       W1, b1, W2, b2, A1, ab1, A2, ab2, A3, ab3,
                       out, N, L, nwaves);
}

// Round 10
// 48.460 us; speedup vs baseline: 1.1128x; 1.1128x over previous
//
#include <hip/hip_runtime.h>
#include <hip/hip_bf16.h>
#include <stdint.h>

typedef short bfx8 __attribute__((ext_vector_type(8)));
typedef float f32x4 __attribute__((ext_vector_type(4)));

#define MFMA16(a, b, c) __builtin_amdgcn_mfma_f32_16x16x32_bf16(a, b, c, 0, 0, 0)
// 0x77: ALU/VALU/SALU/VMEM may cross; DS_READ/DS_WRITE/MFMA pinned
#define STAGE_FENCE() __builtin_amdgcn_sched_barrier(0x77)
// 0x47: additionally pins VMEM_READ (keeps prefetch loads ABOVE this point)
#define PIN_FENCE()   __builtin_amdgcn_sched_barrier(0x47)

// cb layout (floats)
#define CB_B1  0
#define CB_B2  64
#define CB_AB1 128
#define CB_AB2 192
#define CB_A3  256
#define CB_AB3 320

__device__ __forceinline__ uint32_t pk2(float a, float b) {
    __hip_bfloat162 h = __float22bfloat162_rn(make_float2(a, b)); // low=a, high=b
    union { __hip_bfloat162 h; uint32_t u; } cv; cv.h = h; return cv.u;
}
__device__ __forceinline__ float bflo(uint32_t w) { return __uint_as_float(w << 16); }
__device__ __forceinline__ float bfhi(uint32_t w) { return __uint_as_float(w & 0xFFFF0000u); }

__device__ __forceinline__ bfx8 pack8(const float4 a, const float4 b) {
    union { bfx8 v; uint32_t u[4]; } r;
    r.u[0] = pk2(a.x, a.y); r.u[1] = pk2(a.z, a.w);
    r.u[2] = pk2(b.x, b.y); r.u[3] = pk2(b.z, b.w);
    return r.v;
}
// relu + pack two acc quads (a = dims +0..3, b = dims +4..7)
__device__ __forceinline__ bfx8 packr(f32x4 a, f32x4 b) {
    union { bfx8 v; uint32_t u[4]; } r;
    r.u[0] = pk2(fmaxf(a[0], 0.f), fmaxf(a[1], 0.f));
    r.u[1] = pk2(fmaxf(a[2], 0.f), fmaxf(a[3], 0.f));
    r.u[2] = pk2(fmaxf(b[0], 0.f), fmaxf(b[1], 0.f));
    r.u[3] = pk2(fmaxf(b[2], 0.f), fmaxf(b[3], 0.f));
    return r.v;
}
__device__ __forceinline__ float4 ld4(const float* p) { return *(const float4*)p; }

// bank-spread XOR mixes (row bits that vary across the 16 A-rows: 0,1,3,4)
__device__ __forceinline__ int mix4(int row) {
    return (row & 3) | (((row >> 4) & 1) << 2) | (((row >> 3) & 1) << 3);
}
__device__ __forceinline__ int mix3(int row) {
    return (row & 3) | (((row >> 3) & 1) << 2);
}
// weight fragment loads: 256B-row (K=128) and 128B-row (K=64) arrays
__device__ __forceinline__ bfx8 ldw4(const uint8_t* base, int row, int c, int g) {
    int chunk = (4 * c + g) ^ mix4(row);
    return *(const bfx8*)(base + row * 256 + chunk * 16);
}
__device__ __forceinline__ bfx8 ldw2(const uint8_t* base, int row, int c, int g) {
    int chunk = ((4 * c + g) ^ mix3(row)) & 7;
    return *(const bfx8*)(base + row * 128 + chunk * 16);
}
// DPP 16-lane row reduction (VALU only, no LDS); ctrl must be compile-time
template <int CTRL>
__device__ __forceinline__ float dppadd(float x) {
    int y = __builtin_amdgcn_update_dpp(0, __float_as_int(x), CTRL, 0xF, 0xF, false);
    return x + __int_as_float(y);
}
__device__ __forceinline__ float rowsum16(float x) {
    x = dppadd<0xB1>(x);    // quad_perm(1,0,3,2) : xor1
    x = dppadd<0x4E>(x);    // quad_perm(2,3,0,1) : xor2
    x = dppadd<0x124>(x);   // row_ror:4
    x = dppadd<0x128>(x);   // row_ror:8
    return x;
}

__global__ __launch_bounds__(512, 1) void uvagg_mfma(
    const int* __restrict__ nodes, const int* __restrict__ huv,
    const int* __restrict__ hr, const int* __restrict__ hlen,
    const float* __restrict__ v2e, const float* __restrict__ u2e,
    const float* __restrict__ r2e,
    const float* __restrict__ W1, const float* __restrict__ b1,
    const float* __restrict__ W2, const float* __restrict__ b2,
    const float* __restrict__ A1, const float* __restrict__ ab1,
    const float* __restrict__ A2, const float* __restrict__ ab2,
    const float* __restrict__ A3, const float* __restrict__ ab3f,
    float* __restrict__ out, int N, int L, int nwaves)
{
    __shared__ __align__(16) uint8_t W1s[64 * 256];
    __shared__ __align__(16) uint8_t A1s[64 * 256];
    __shared__ __align__(16) uint8_t W2s[64 * 128];
    __shared__ __align__(16) uint8_t A2s[64 * 128];
    __shared__ __align__(16) float cb[324];

    const int tid = threadIdx.x;
    // stage W1/A1: 4096 k-pairs each; thread handles (2kp, 2kp+1) x d
    for (int i = tid; i < 4096; i += 512) {
        int kp = i >> 6, d = i & 63;
        int addr = d * 256 + ((((kp >> 2) ^ mix4(d)) & 15) << 4) + ((kp & 3) << 2);
        *(uint32_t*)(W1s + addr) = pk2(W1[(2 * kp) * 64 + d], W1[(2 * kp + 1) * 64 + d]);
        *(uint32_t*)(A1s + addr) = pk2(A1[(2 * kp) * 64 + d], A1[(2 * kp + 1) * 64 + d]);
    }
    // stage W2/A2: 2048 k-pairs each
    for (int i = tid; i < 2048; i += 512) {
        int kp = i >> 6, d = i & 63;
        int addr = d * 128 + ((((kp >> 2) ^ mix3(d)) & 7) << 4) + ((kp & 3) << 2);
        *(uint32_t*)(W2s + addr) = pk2(W2[(2 * kp) * 64 + d], W2[(2 * kp + 1) * 64 + d]);
        *(uint32_t*)(A2s + addr) = pk2(A2[(2 * kp) * 64 + d], A2[(2 * kp + 1) * 64 + d]);
    }
    for (int i = tid; i < 321; i += 512) {
        if (i < 64)       cb[CB_B1 + i]        = b1[i];
        else if (i < 128) cb[CB_B2 + i - 64]   = b2[i - 64];
        else if (i < 192) cb[CB_AB1 + i - 128] = ab1[i - 128];
        else if (i < 256) cb[CB_AB2 + i - 192] = ab2[i - 192];
        else if (i < 320) cb[CB_A3 + i - 256]  = A3[i - 256];
        else              cb[CB_AB3]           = ab3f[0];
    }
    __syncthreads();

    const int lane = tid & 63;
    const int wid  = tid >> 6;
    const int s    = lane & 15;          // slot-in-tile (matrix column)
    const int g    = lane >> 4;          // k-group
    const int rs   = 8 * (s >> 2) + (s & 3);  // pi-permuted A-row base
    const float ab3 = cb[CB_AB3];

    for (int node = blockIdx.x * 8 + wid; node < N; node += nwaves) {
        const int hl = __builtin_amdgcn_readfirstlane(min(hlen[node], L));
        const int un = __builtin_amdgcn_readfirstlane(nodes[node]);

        // urep B-frags: A1 k-cols 64..127 (natural k order)
        const float* ur = u2e + (size_t)un * 64;
        const bfx8 uf2 = pack8(ld4(ur + 8 * g),      ld4(ur + 8 * g + 4));
        const bfx8 uf3 = pack8(ld4(ur + 32 + 8 * g), ld4(ur + 36 + 8 * g));

        // preload ALL history indices for this node (lane-spread, one level)
        const int idxlane = min(lane, L - 1);
        const int iu_all = huv[(size_t)node * L + idxlane];
        const int ir_all = hr [(size_t)node * L + idxlane];

        // ---- once per node: h1base = ab1 + A1^T[k=64..127] . urep
        //      (this half of stage 3 is slot-independent; hoisted out of the
        //       tile loop: saves 8 MFMA + 8 ds_read_b128 per tile)
        f32x4 h1base[4];
        #pragma unroll
        for (int mt = 0; mt < 4; ++mt) {
            const int dof = 4 * (mt & 1) + 32 * (mt >> 1);
            h1base[mt] = *(const f32x4*)(cb + CB_AB1 + 8 * g + dof);
            const int row = rs + dof;
            h1base[mt] = MFMA16(ldw4(A1s, row, 2, g), uf2, h1base[mt]);
            h1base[mt] = MFMA16(ldw4(A1s, row, 3, g), uf3, h1base[mt]);
        }

        float zacc = 0.0f;
        f32x4 accO[4];
        #pragma unroll
        for (int i = 0; i < 4; ++i) accO[i] = f32x4{0.f, 0.f, 0.f, 0.f};

        const int ntile = (hl + 15) >> 4;

        // ---- pipeline prologue: issue tile-0 embedding loads
        float4 qa0, qa1, qa2, qa3, qb0, qb1, qb2, qb3;
        {
            const int slot0 = min(s, hl - 1);
            const int iu = __shfl(iu_all, slot0, 64);
            const int ir = __shfl(ir_all, slot0, 64);
            const float* vr = v2e + (size_t)iu * 64;
            const float* rr = r2e + (size_t)ir * 64;
            qa0 = ld4(vr + 8 * g);      qa1 = ld4(vr + 8 * g + 4);
            qa2 = ld4(vr + 32 + 8 * g); qa3 = ld4(vr + 36 + 8 * g);
            qb0 = ld4(rr + 8 * g);      qb1 = ld4(rr + 8 * g + 4);
            qb2 = ld4(rr + 32 + 8 * g); qb3 = ld4(rr + 36 + 8 * g);
        }

        for (int tt = 0; tt < ntile; ++tt) {
            const int gslot = tt * 16 + s;
            // pack current tile's fragments from prefetched raw floats
            const bfx8 f0 = pack8(qa0, qa1);
            const bfx8 f1 = pack8(qa2, qa3);
            const bfx8 f2 = pack8(qb0, qb1);
            const bfx8 f3 = pack8(qb2, qb3);

            // ---- stage 1: x1 = relu(W1^T X + b1), pi-permuted rows
            f32x4 ah[4];
            #pragma unroll
            for (int mt = 0; mt < 4; ++mt) {
                const int dof = 4 * (mt & 1) + 32 * (mt >> 1);
                ah[mt] = *(const f32x4*)(cb + CB_B1 + 8 * g + dof);
                const int row = rs + dof;
                ah[mt] = MFMA16(ldw4(W1s, row, 0, g), f0, ah[mt]);
                ah[mt] = MFMA16(ldw4(W1s, row, 1, g), f1, ah[mt]);
                ah[mt] = MFMA16(ldw4(W1s, row, 2, g), f2, ah[mt]);
                ah[mt] = MFMA16(ldw4(W1s, row, 3, g), f3, ah[mt]);
            }
            const bfx8 x1a = packr(ah[0], ah[1]);   // dims 8g..8g+7
            const bfx8 x1b = packr(ah[2], ah[3]);   // dims 32+8g..

            // ---- prefetch next tile's embeddings (wave-uniform guard);
            //      they land during stages 2-4 (~600+ cy of cover)
            if (tt + 1 < ntile) {
                const int nslot = min(tt * 16 + 16 + s, hl - 1);
                const int niu = __shfl(iu_all, nslot, 64);
                const int nir = __shfl(ir_all, nslot, 64);
                const float* vr = v2e + (size_t)niu * 64;
                const float* rr = r2e + (size_t)nir * 64;
                qa0 = ld4(vr + 8 * g);      qa1 = ld4(vr + 8 * g + 4);
                qa2 = ld4(vr + 32 + 8 * g); qa3 = ld4(vr + 36 + 8 * g);
                qb0 = ld4(rr + 8 * g);      qb1 = ld4(rr + 8 * g + 4);
                qb2 = ld4(rr + 32 + 8 * g); qb3 = ld4(rr + 36 + 8 * g);
            }
            PIN_FENCE();   // VMEM_READ may not sink below here

            // ---- stage 2: o = relu(W2^T x1 + b2); immediately pack to bf16
            f32x4 ao[4];
            #pragma unroll
            for (int mt = 0; mt < 4; ++mt) {
                const int dof = 4 * (mt & 1) + 32 * (mt >> 1);
                ao[mt] = *(const f32x4*)(cb + CB_B2 + 8 * g + dof);
                const int row = rs + dof;
                ao[mt] = MFMA16(ldw2(W2s, row, 0, g), x1a, ao[mt]);
                ao[mt] = MFMA16(ldw2(W2s, row, 1, g), x1b, ao[mt]);
            }
            const bfx8 oa = packr(ao[0], ao[1]);
            const bfx8 ob = packr(ao[2], ao[3]);
            STAGE_FENCE();

            // ---- stage 3 (o-half only): h1 = relu(h1base + A1^T[k<64] . o)
            f32x4 h[4];
            #pragma unroll
            for (int mt = 0; mt < 4; ++mt) {
                h[mt] = h1base[mt];
                const int row = rs + 4 * (mt & 1) + 32 * (mt >> 1);
                h[mt] = MFMA16(ldw4(A1s, row, 0, g), oa, h[mt]);
                h[mt] = MFMA16(ldw4(A1s, row, 1, g), ob, h[mt]);
            }
            const bfx8 h1a = packr(h[0], h[1]);
            const bfx8 h1b = packr(h[2], h[3]);
            STAGE_FENCE();

            // ---- stage 4: h2 = relu(A2^T h1 + ab2); fused logit dot with A3
            float part = 0.0f;
            #pragma unroll
            for (int mt = 0; mt < 4; ++mt) {
                const int dof = 4 * (mt & 1) + 32 * (mt >> 1);
                f32x4 h2 = *(const f32x4*)(cb + CB_AB2 + 8 * g + dof);
                const int row = rs + dof;
                h2 = MFMA16(ldw2(A2s, row, 0, g), h1a, h2);
                h2 = MFMA16(ldw2(A2s, row, 1, g), h1b, h2);
                const f32x4 aq = *(const f32x4*)(cb + CB_A3 + 8 * g + dof);
                part = fmaf(fmaxf(h2[0], 0.f), aq[0], part);
                part = fmaf(fmaxf(h2[1], 0.f), aq[1], part);
                part = fmaf(fmaxf(h2[2], 0.f), aq[2], part);
                part = fmaf(fmaxf(h2[3], 0.f), aq[3], part);
            }
            STAGE_FENCE();
            // cross-g reduce (lanes s, s+16, s+32, s+48)
            float p2 = part + __shfl_xor(part, 16, 64);
            const float sl = p2 + __shfl_xor(p2, 32, 64) + ab3;
            // no-max softmax (logits are tiny; exp is exact softmax up to shift)
            const float p = (gslot < hl) ? __expf(sl) : 0.0f;
            zacc += p;
            // accumulate p * o from the bf16-packed oa/ob (unpack = shift/mask)
            union { bfx8 v; uint32_t u[4]; } ua, ub;
            ua.v = oa; ub.v = ob;
            #pragma unroll
            for (int j = 0; j < 2; ++j) {
                accO[0][2*j+0] = fmaf(p, bflo(ua.u[j]),     accO[0][2*j+0]);
                accO[0][2*j+1] = fmaf(p, bfhi(ua.u[j]),     accO[0][2*j+1]);
                accO[1][2*j+0] = fmaf(p, bflo(ua.u[2 + j]), accO[1][2*j+0]);
                accO[1][2*j+1] = fmaf(p, bfhi(ua.u[2 + j]), accO[1][2*j+1]);
                accO[2][2*j+0] = fmaf(p, bflo(ub.u[j]),     accO[2][2*j+0]);
                accO[2][2*j+1] = fmaf(p, bfhi(ub.u[j]),     accO[2][2*j+1]);
                accO[3][2*j+0] = fmaf(p, bflo(ub.u[2 + j]), accO[3][2*j+0]);
                accO[3][2*j+1] = fmaf(p, bfhi(ub.u[2 + j]), accO[3][2*j+1]);
            }
        }

        // final reductions over the 16 slot-lanes: DPP only
        const float Z = rowsum16(zacc);
        #pragma unroll
        for (int mt = 0; mt < 4; ++mt)
            #pragma unroll
            for (int r = 0; r < 4; ++r)
                accO[mt][r] = rowsum16(accO[mt][r]);
        const float inv = 1.0f / Z;
        if (s == 0) {
            float* op = out + (size_t)node * 64;
            #pragma unroll
            for (int mt = 0; mt < 4; ++mt) {
                const int dof = 8 * g + 4 * (mt & 1) + 32 * (mt >> 1);
                *(float4*)(op + dof) = make_float4(accO[mt][0] * inv, accO[mt][1] * inv,
                                                   accO[mt][2] * inv, accO[mt][3] * inv);
            }
        }
    }
}

extern "C" void kernel_launch(void* const* d_in, const int* in_sizes, int n_in,
                              void* d_out, int out_size, void* d_ws, size_t ws_size,
                              hipStream_t stream) {
    const int*   nodes = (const int*)d_in[0];
    const int*   huv   = (const int*)d_in[1];
    const int*   hrr   = (const int*)d_in[2];
    const int*   hlen  = (const int*)d_in[3];
    const float* v2e   = (const float*)d_in[4];
    const float* u2e   = (const float*)d_in[5];
    const float* r2e   = (const float*)d_in[6];
    const float* W1    = (const float*)d_in[7];
    const float* b1    = (const float*)d_in[8];
    const float* W2    = (const float*)d_in[9];
    const float* b2    = (const float*)d_in[10];
    const float* A1    = (const float*)d_in[11];
    const float* ab1   = (const float*)d_in[12];
    const float* A2    = (const float*)d_in[13];
    const float* ab2   = (const float*)d_in[14];
    const float* A3    = (const float*)d_in[15];
    const float* ab3   = (const float*)d_in[16];
    float* out = (float*)d_out;

    const int N = in_sizes[0];
    const int L = in_sizes[1] / N;
    // persistent grid: exactly the co-resident capacity (2 blocks/CU x 256 CU)
    int blocks = (N + 7) / 8;
    if (blocks > 512) blocks = 512;
    const int nwaves = blocks * 8;

    hipLaunchKernelGGL(uvagg_mfma, dim3(blocks), dim3(512), 0, stream,
                       nodes, huv, hrr, hlen, v2e, u2e, r2e,
                       W1, b1, W2, b2, A1, ab1, A2, ab2, A3, ab3,
                       out, N, L, nwaves);
}